// Round 3
// baseline (3401.795 us; speedup 1.0000x reference)
//
#include <hip/hip_runtime.h>

// NeuralConvNetwork (Duvenaud fingerprint GNN), MI355X.
// Round 3: all float tensors are fp32 (per harness contract: "float32 -> const
// float*"). R1/R2's inf came from reading fp32 buffers as bf16: float mantissa
// halves form bf16 NaN patterns -> ss=NaN -> fmaxf(NaN,1e-12)=1e-12 -> rn=1e12
// -> overflow -> inf in d_out. Intermediates are stored bf16 in workspace
// (halves footprint/traffic; ~0.4% rel err << 2% threshold).
//   - 40-atom tiles: degree boundaries (100k/275k/425k) and molecule boundaries
//     (20 atoms) all multiples of 40 -> one degree per block, 2 mols per block.
//   - Per layer: H = [x_i | sum_nbr x | sum_nbr bond] staged in LDS (fp32),
//     register-tiled GEMM vs [Ws ; Wd[deg]] (fp32 weights from global/L2),
//     bias + L2-normalize + ReLU epilogue. Layer 3 fuses the per-molecule
//     segment sum (no atomics). Output fp32.

#define XSTRIDE 104   // bf16 row stride for intermediate activations (F<=100)

__device__ __forceinline__ float bf2f(unsigned short u) {
    return __uint_as_float(((unsigned)u) << 16);
}
__device__ __forceinline__ unsigned short f2bf(float f) {
    unsigned b = __float_as_uint(f);
    return (unsigned short)((b + 0x7FFFu + ((b >> 16) & 1u)) >> 16);  // RNE
}

template<bool BF16IN>
__device__ __forceinline__ float ldx(const void* p, size_t idx) {
    if constexpr (BF16IN) return bf2f(((const unsigned short*)p)[idx]);
    else                  return ((const float*)p)[idx];
}

template<int NC>
__device__ __forceinline__ void loadw(const float* p, float* w) {
    if constexpr (NC == 8) {
        float4 a = *(const float4*)p;        // offsets multiple of 8 floats -> 16B ok
        float4 b = *(const float4*)(p + 4);
        w[0] = a.x; w[1] = a.y; w[2] = a.z; w[3] = a.w;
        w[4] = b.x; w[5] = b.y; w[6] = b.z; w[7] = b.w;
    } else {
        float2 a = *(const float2*)p;        // offsets even -> 8B aligned
        w[0] = a.x; w[1] = a.y;
    }
}

template<int F_IN, int F_OUT, int NC, bool LAST, bool BF16IN>
__global__ __launch_bounds__(256, 2) void layer_kernel(
    const void* __restrict__ xin, int xstride,
    const float* __restrict__ bondf,
    const int* __restrict__ an1, const int* __restrict__ bn1,
    const int* __restrict__ an2, const int* __restrict__ bn2,
    const int* __restrict__ an3, const int* __restrict__ bn3,
    const int* __restrict__ an4, const int* __restrict__ bn4,
    const float* __restrict__ Ws, const float* __restrict__ bsv,
    const float* __restrict__ Wd, const float* __restrict__ bdv,
    unsigned short* __restrict__ xout,      // layers 0/1: [500000, XSTRIDE] bf16
    float* __restrict__ molout)             // layer 2:    [25000, 512] fp32
{
    constexpr int K_NB = F_IN + 6;                  // neighbor-GEMM K (atom+bond)
    constexpr int KS   = ((2 * F_IN + 6) + 3) & ~3; // padded LDS row length
    __shared__ float Hs[40 * KS];                   // H[r][k]
    __shared__ float Sc[LAST ? 1024 : 4];           // mol partial scratch

    const int R0 = blockIdx.x * 40;
    int deg, seg;
    if (R0 < 100000)      { deg = 1; seg = 0;      }
    else if (R0 < 275000) { deg = 2; seg = 100000; }
    else if (R0 < 425000) { deg = 3; seg = 275000; }
    else                  { deg = 4; seg = 425000; }
    const int* an = (deg == 1) ? an1 : (deg == 2) ? an2 : (deg == 3) ? an3 : an4;
    const int* bn = (deg == 1) ? bn1 : (deg == 2) ? bn2 : (deg == 3) ? bn3 : bn4;

    // ---- phase 1: build H in LDS. cols [0,F_IN)=self x, [F_IN,2F_IN)=sum_nbr x,
    //      [2F_IN,2F_IN+6)=sum_nbr bond.
    {
        const int rblk = threadIdx.x >> 7;     // 2 rows in flight
        const int k    = threadIdx.x & 127;
        for (int rb = 0; rb < 40; rb += 2) {
            const int r    = rb + rblk;
            const int atom = R0 + r;
            const int ri   = atom - seg;       // index within degree segment
            if (k < F_IN) {
                float self = ldx<BF16IN>(xin, (size_t)atom * xstride + k);
                float asum = 0.f;
                const int* anr = an + (size_t)ri * deg;
                for (int j = 0; j < deg; ++j)
                    asum += ldx<BF16IN>(xin, (size_t)anr[j] * xstride + k);
                Hs[r * KS + k]        = self;
                Hs[r * KS + F_IN + k] = asum;
            }
            if (k < 6) {
                float bsum = 0.f;
                const int* bnr = bn + (size_t)ri * deg;
                for (int j = 0; j < deg; ++j)
                    bsum += bondf[(size_t)bnr[j] * 6 + k];
                Hs[r * KS + 2 * F_IN + k] = bsum;
            }
        }
    }
    __syncthreads();

    // ---- phase 2: register-tiled GEMM. wave wv owns rows [wv*10, wv*10+10),
    //      lane owns NC consecutive output cols. H reads are wave-uniform LDS
    //      broadcasts; fp32 weights stream from global (L2-resident).
    const int lane   = threadIdx.x & 63;
    const int wv     = threadIdx.x >> 6;
    const int c0     = lane * NC;
    const bool cvalid = (c0 < F_OUT);          // F_OUT=100: lanes >=50 idle
    const int rbase  = wv * 10;

    float acc[10][NC];
    #pragma unroll
    for (int r = 0; r < 10; ++r)
        #pragma unroll
        for (int j = 0; j < NC; ++j) acc[r][j] = 0.f;

    if (cvalid) {
        const float* hrow = &Hs[rbase * KS];
        #pragma unroll 2
        for (int k = 0; k < F_IN; ++k) {       // self part: x @ Ws
            float w[NC];
            loadw<NC>(Ws + (size_t)k * F_OUT + c0, w);
            float h[10];
            #pragma unroll
            for (int r = 0; r < 10; ++r) h[r] = hrow[r * KS + k];
            #pragma unroll
            for (int r = 0; r < 10; ++r)
                #pragma unroll
                for (int j = 0; j < NC; ++j)
                    acc[r][j] = fmaf(h[r], w[j], acc[r][j]);
        }
        const float* Wdd = Wd + (size_t)(deg - 1) * K_NB * F_OUT;
        #pragma unroll 2
        for (int k = 0; k < K_NB; ++k) {       // neighbor part: [asum|bsum] @ Wd[deg]
            float w[NC];
            loadw<NC>(Wdd + (size_t)k * F_OUT + c0, w);
            float h[10];
            #pragma unroll
            for (int r = 0; r < 10; ++r) h[r] = hrow[r * KS + F_IN + k];
            #pragma unroll
            for (int r = 0; r < 10; ++r)
                #pragma unroll
                for (int j = 0; j < NC; ++j)
                    acc[r][j] = fmaf(h[r], w[j], acc[r][j]);
        }
    }

    // ---- phase 3: bias + L2-row-normalize + ReLU (+ fused mol segment-sum)
    float bias[NC];
    #pragma unroll
    for (int j = 0; j < NC; ++j)
        bias[j] = cvalid ? (bsv[c0 + j] + bdv[(deg - 1) * F_OUT + c0 + j]) : 0.f;

    if constexpr (!LAST) {
        for (int rr = 0; rr < 10; ++rr) {
            float t[NC]; float ss = 0.f;
            #pragma unroll
            for (int j = 0; j < NC; ++j) {
                t[j] = cvalid ? (acc[rr][j] + bias[j]) : 0.f;
                ss += t[j] * t[j];
            }
            #pragma unroll
            for (int off = 32; off; off >>= 1) ss += __shfl_xor(ss, off);
            const float rn = 1.0f / fmaxf(sqrtf(ss), 1e-12f);
            if (cvalid) {
                unsigned pr = (unsigned)f2bf(fmaxf(t[0] * rn, 0.f))
                            | ((unsigned)f2bf(fmaxf(t[1] * rn, 0.f)) << 16);
                *(unsigned*)(xout + (size_t)(R0 + rbase + rr) * XSTRIDE + c0) = pr;
            }
        }
    } else {
        // rows 0..19 -> mol R0/20, rows 20..39 -> mol R0/20+1
        float msum[NC];
        #pragma unroll
        for (int j = 0; j < NC; ++j) msum[j] = 0.f;
        for (int rr = 0; rr < 10; ++rr) {
            float t[NC]; float ss = 0.f;
            #pragma unroll
            for (int j = 0; j < NC; ++j) {
                t[j] = acc[rr][j] + bias[j];
                ss += t[j] * t[j];
            }
            #pragma unroll
            for (int off = 32; off; off >>= 1) ss += __shfl_xor(ss, off);
            const float rn = 1.0f / fmaxf(sqrtf(ss), 1e-12f);
            #pragma unroll
            for (int j = 0; j < NC; ++j) msum[j] += fmaxf(t[j] * rn, 0.f);
        }
        if (wv & 1) {   // waves 1,3 hand partials to waves 0,2
            #pragma unroll
            for (int j = 0; j < NC; ++j)
                Sc[(((wv >> 1) * 64) + lane) * 8 + j] = msum[j];
        }
        __syncthreads();
        if (!(wv & 1)) {
            const int mol = R0 / 20 + (wv >> 1);
            float tot[8];
            #pragma unroll
            for (int j = 0; j < NC; ++j)
                tot[j] = msum[j] + Sc[(((wv >> 1) * 64) + lane) * 8 + j];
            float* op = molout + (size_t)mol * 512 + c0;
            *(float4*)(op)     = make_float4(tot[0], tot[1], tot[2], tot[3]);
            *(float4*)(op + 4) = make_float4(tot[4], tot[5], tot[6], tot[7]);
        }
    }
}

extern "C" void kernel_launch(void* const* d_in, const int* in_sizes, int n_in,
                              void* d_out, int out_size, void* d_ws, size_t ws_size,
                              hipStream_t stream) {
    // Detect input ordering (robust to dict-vs-signature order).
    //   dict order      : an1,bn1,an2,bn2,... ; Ws0,bs0,Wd0,bd0, Ws1,...
    //   signature order : an1,an2,an3,an4,bn1,... ; Ws0,bs0,Ws1,bs1,Ws2,bs2, Wd0,bd0,...
    // in_sizes[3]: dict -> bn1 = 100000 ; signature -> an2 = 350000.
    const bool sig_order = (in_sizes[3] != 100000);

    const float* atomf = (const float*)d_in[0];   // [500000,62]
    const float* bondf = (const float*)d_in[1];   // [600000,6]
    const int *an1, *bn1, *an2, *bn2, *an3, *bn3, *an4, *bn4;
    const float *Ws0, *bs0, *Wd0, *bd0;
    const float *Ws1, *bs1, *Wd1, *bd1;
    const float *Ws2, *bs2, *Wd2, *bd2;

    if (!sig_order) {
        an1 = (const int*)d_in[2];  bn1 = (const int*)d_in[3];
        an2 = (const int*)d_in[4];  bn2 = (const int*)d_in[5];
        an3 = (const int*)d_in[6];  bn3 = (const int*)d_in[7];
        an4 = (const int*)d_in[8];  bn4 = (const int*)d_in[9];
        Ws0 = (const float*)d_in[11]; bs0 = (const float*)d_in[12];
        Wd0 = (const float*)d_in[13]; bd0 = (const float*)d_in[14];
        Ws1 = (const float*)d_in[15]; bs1 = (const float*)d_in[16];
        Wd1 = (const float*)d_in[17]; bd1 = (const float*)d_in[18];
        Ws2 = (const float*)d_in[19]; bs2 = (const float*)d_in[20];
        Wd2 = (const float*)d_in[21]; bd2 = (const float*)d_in[22];
    } else {
        an1 = (const int*)d_in[2];  an2 = (const int*)d_in[3];
        an3 = (const int*)d_in[4];  an4 = (const int*)d_in[5];
        bn1 = (const int*)d_in[6];  bn2 = (const int*)d_in[7];
        bn3 = (const int*)d_in[8];  bn4 = (const int*)d_in[9];
        Ws0 = (const float*)d_in[11]; bs0 = (const float*)d_in[12];
        Ws1 = (const float*)d_in[13]; bs1 = (const float*)d_in[14];
        Ws2 = (const float*)d_in[15]; bs2 = (const float*)d_in[16];
        Wd0 = (const float*)d_in[17]; bd0 = (const float*)d_in[18];
        Wd1 = (const float*)d_in[19]; bd1 = (const float*)d_in[20];
        Wd2 = (const float*)d_in[21]; bd2 = (const float*)d_in[22];
    }

    unsigned short* x1 = (unsigned short*)d_ws;                      // [500000,104] bf16
    unsigned short* x2 = x1 + (size_t)500000 * XSTRIDE;              // [500000,104] bf16

    dim3 grid(12500), block(256);
    layer_kernel<62, 100, 2, false, false><<<grid, block, 0, stream>>>(
        atomf, 62, bondf, an1, bn1, an2, bn2, an3, bn3, an4, bn4,
        Ws0, bs0, Wd0, bd0, x1, nullptr);
    layer_kernel<100, 100, 2, false, true><<<grid, block, 0, stream>>>(
        x1, XSTRIDE, bondf, an1, bn1, an2, bn2, an3, bn3, an4, bn4,
        Ws1, bs1, Wd1, bd1, x2, nullptr);
    layer_kernel<100, 512, 8, true, true><<<grid, block, 0, stream>>>(
        x2, XSTRIDE, bondf, an1, bn1, an2, bn2, an3, bn3, an4, bn4,
        Ws2, bs2, Wd2, bd2, nullptr, (float*)d_out);
}

// Round 4
// 1505.856 us; speedup vs baseline: 2.2590x; 2.2590x over previous
//
#include <hip/hip_runtime.h>

// NeuralConvNetwork (Duvenaud fingerprint GNN), MI355X.
// Round 4: MFMA conversion. R3 (passed, 3402 us) was fp32-VALU-bound
// (MfmaUtil=0, VALUBusy 63%, HBM 3%). GEMM phase now uses
// v_mfma_f32_16x16x32_bf16 on a 48x{160,224} H tile (40 real rows + 8 zero
// pad; 40 | degree boundaries and covers 2 molecules exactly).
//   - prep kernels pack combined weights [Ws;Wd[deg]] as bf16 Wt[deg][n][k]
//     (B-fragment layout: lane n reads 8 contiguous k = 16B) + fused bias.
//   - H (bf16) staged in LDS, stride KP+8 (2-way bank aliasing only).
//   - epilogue in C-fragment registers: bias, ssq via quad shfl_xor + small
//     LDS cross-wave combine, L2-normalize + ReLU; layer 3 fuses the
//     per-molecule segment sum in-register (shfl_xor 16/32), no atomics.

#define XS 100   // bf16 elems per intermediate activation row

typedef __attribute__((ext_vector_type(8))) short short8;
typedef __attribute__((ext_vector_type(4))) float float4v;

__device__ __forceinline__ float bf2f(unsigned u) {
    return __uint_as_float(u << 16);
}
__device__ __forceinline__ unsigned short f2bf(float f) {
    unsigned b = __float_as_uint(f);
    return (unsigned short)((b + 0x7FFFu + ((b >> 16) & 1u)) >> 16);  // RNE
}

// ---- weight prep: Wt[dg][n][k] = k<F_IN ? Ws[k][n] : k<2F_IN+6 ? Wd[dg][k-F_IN][n] : 0
__global__ void prep_weights(const float* __restrict__ Ws, const float* __restrict__ bs,
                             const float* __restrict__ Wd, const float* __restrict__ bd,
                             int F_IN, int F_OUT, int F_OUT_PAD, int KP,
                             unsigned short* __restrict__ Wt, float* __restrict__ bc)
{
    int id = blockIdx.x * 256 + threadIdx.x;
    int total = 4 * F_OUT_PAD * KP;
    if (id >= total) return;
    int k  = id % KP;
    int nq = (id / KP) % F_OUT_PAD;
    int dg = id / (KP * F_OUT_PAD);
    float v = 0.f;
    if (nq < F_OUT) {
        if (k < F_IN)               v = Ws[(size_t)k * F_OUT + nq];
        else if (k < 2 * F_IN + 6)  v = Wd[((size_t)dg * (F_IN + 6) + (k - F_IN)) * F_OUT + nq];
    }
    Wt[id] = f2bf(v);
    if (k == 0)
        bc[dg * F_OUT_PAD + nq] = (nq < F_OUT) ? (bs[nq] + bd[(size_t)dg * F_OUT + nq]) : 0.f;
}

template<int F_IN, int F_OUT, int F_OUT_PAD, bool LAST, bool BF16IN>
__global__ __launch_bounds__(256) void layer_mfma(
    const void* __restrict__ xin,
    const float* __restrict__ bondf,
    const int* __restrict__ an1, const int* __restrict__ bn1,
    const int* __restrict__ an2, const int* __restrict__ bn2,
    const int* __restrict__ an3, const int* __restrict__ bn3,
    const int* __restrict__ an4, const int* __restrict__ bn4,
    const unsigned short* __restrict__ Wt,  // [4][F_OUT_PAD][KP] bf16
    const float* __restrict__ bcomb,        // [4][F_OUT_PAD] fp32
    unsigned short* __restrict__ xout,      // layers 0/1: [500000, XS] bf16
    float* __restrict__ molout)             // layer 2:    [25000, 512] fp32
{
    constexpr int KTOT = 2 * F_IN + 6;
    constexpr int KP   = (KTOT + 31) & ~31;   // 160 / 224
    constexpr int SP   = KP + 8;              // LDS row stride (bf16): 2-way banks only
    constexpr int NT   = F_OUT_PAD / 16;      // 7 / 32
    constexpr int JMAX = (NT + 3) / 4;        // 2 / 8

    __shared__ __align__(16) unsigned short Hs[48 * SP];
    __shared__ float ssqs[4][48];

    const int R0 = blockIdx.x * 40;
    int deg, seg;
    if (R0 < 100000)      { deg = 1; seg = 0;      }
    else if (R0 < 275000) { deg = 2; seg = 100000; }
    else if (R0 < 425000) { deg = 3; seg = 275000; }
    else                  { deg = 4; seg = 425000; }
    const int* an = (deg == 1) ? an1 : (deg == 2) ? an2 : (deg == 3) ? an3 : an4;
    const int* bn = (deg == 1) ? bn1 : (deg == 2) ? bn2 : (deg == 3) ? bn3 : bn4;

    // ---- zero H (covers pad rows 40..47 and k-pad [KTOT,KP))
    for (int i = threadIdx.x; i < 48 * SP / 2; i += 256) ((unsigned*)Hs)[i] = 0;
    __syncthreads();

    // ---- gather: H[r] = [x_self (F_IN) | sum_nbr x (F_IN) | sum_nbr bond (6)]
    {
        const int r8 = threadIdx.x >> 5;   // 8 rows in flight
        const int c  = threadIdx.x & 31;
        for (int rb = 0; rb < 40; rb += 8) {
            const int r    = rb + r8;
            const int atom = R0 + r;
            const int ri   = atom - seg;
            const int* anr = an + (size_t)ri * deg;
            const int* bnr = bn + (size_t)ri * deg;
            if constexpr (BF16IN) {
                if (c < 25) {                          // 25*4 = 100 elems
                    const unsigned short* x = (const unsigned short*)xin;
                    *(uint2*)&Hs[r * SP + c * 4] =
                        *(const uint2*)(x + (size_t)atom * XS + c * 4);   // self: bit copy
                    float s0 = 0.f, s1 = 0.f, s2 = 0.f, s3 = 0.f;
                    for (int j = 0; j < deg; ++j) {
                        uint2 v = *(const uint2*)(x + (size_t)anr[j] * XS + c * 4);
                        s0 += bf2f(v.x & 0xFFFFu); s1 += bf2f(v.x >> 16);
                        s2 += bf2f(v.y & 0xFFFFu); s3 += bf2f(v.y >> 16);
                    }
                    uint2 o;
                    o.x = (unsigned)f2bf(s0) | ((unsigned)f2bf(s1) << 16);
                    o.y = (unsigned)f2bf(s2) | ((unsigned)f2bf(s3) << 16);
                    *(uint2*)&Hs[r * SP + F_IN + c * 4] = o;
                }
            } else {
                if (c < 31) {                          // 31*2 = 62 elems
                    const float* x = (const float*)xin;
                    float2 sv = *(const float2*)(x + (size_t)atom * F_IN + c * 2);
                    Hs[r * SP + c * 2]     = f2bf(sv.x);
                    Hs[r * SP + c * 2 + 1] = f2bf(sv.y);
                    float s0 = 0.f, s1 = 0.f;
                    for (int j = 0; j < deg; ++j) {
                        float2 v = *(const float2*)(x + (size_t)anr[j] * F_IN + c * 2);
                        s0 += v.x; s1 += v.y;
                    }
                    Hs[r * SP + F_IN + c * 2]     = f2bf(s0);
                    Hs[r * SP + F_IN + c * 2 + 1] = f2bf(s1);
                }
            }
            if (c < 6) {
                float bsum = 0.f;
                for (int j = 0; j < deg; ++j) bsum += bondf[(size_t)bnr[j] * 6 + c];
                Hs[r * SP + 2 * F_IN + c] = f2bf(bsum);
            }
        }
    }
    __syncthreads();

    // ---- MFMA GEMM: 3 M-tiles (48 rows) x NT N-tiles, K = KP
    const int lane = threadIdx.x & 63;
    const int wv   = threadIdx.x >> 6;
    const int n16  = lane & 15;
    const int quad = lane >> 4;

    float4v acc[JMAX][3];
    #pragma unroll
    for (int j = 0; j < JMAX; ++j)
        #pragma unroll
        for (int mt = 0; mt < 3; ++mt)
            acc[j][mt] = (float4v){0.f, 0.f, 0.f, 0.f};

    const unsigned short* Wb = Wt + (size_t)(deg - 1) * F_OUT_PAD * KP;

    for (int kk = 0; kk < KP; kk += 32) {
        short8 a[3];
        #pragma unroll
        for (int mt = 0; mt < 3; ++mt)
            a[mt] = *(const short8*)&Hs[(mt * 16 + n16) * SP + kk + quad * 8];
        #pragma unroll
        for (int j = 0; j < JMAX; ++j) {
            const int nt = wv + 4 * j;
            if (nt < NT) {
                short8 b = *(const short8*)(Wb + (size_t)(nt * 16 + n16) * KP + kk + quad * 8);
                #pragma unroll
                for (int mt = 0; mt < 3; ++mt)
                    acc[j][mt] = __builtin_amdgcn_mfma_f32_16x16x32_bf16(
                        a[mt], b, acc[j][mt], 0, 0, 0);
            }
        }
    }

    // ---- epilogue: bias, row ssq (quad shfl + cross-wave LDS), normalize
    // C/D layout: col = nt*16 + n16, row = mt*16 + quad*4 + r
    float ssq[3][4];
    #pragma unroll
    for (int mt = 0; mt < 3; ++mt)
        #pragma unroll
        for (int r = 0; r < 4; ++r) ssq[mt][r] = 0.f;

    #pragma unroll
    for (int j = 0; j < JMAX; ++j) {
        const int nt = wv + 4 * j;
        if (nt < NT) {
            const float bj = bcomb[(deg - 1) * F_OUT_PAD + nt * 16 + n16];
            #pragma unroll
            for (int mt = 0; mt < 3; ++mt)
                #pragma unroll
                for (int r = 0; r < 4; ++r) {
                    float t = acc[j][mt][r] + bj;
                    acc[j][mt][r] = t;
                    ssq[mt][r] += t * t;
                }
        }
    }
    #pragma unroll
    for (int off = 1; off <= 8; off <<= 1)
        #pragma unroll
        for (int mt = 0; mt < 3; ++mt)
            #pragma unroll
            for (int r = 0; r < 4; ++r)
                ssq[mt][r] += __shfl_xor(ssq[mt][r], off);
    if (n16 == 0)
        #pragma unroll
        for (int mt = 0; mt < 3; ++mt)
            #pragma unroll
            for (int r = 0; r < 4; ++r)
                ssqs[wv][mt * 16 + quad * 4 + r] = ssq[mt][r];
    __syncthreads();

    float rn[3][4];
    #pragma unroll
    for (int mt = 0; mt < 3; ++mt)
        #pragma unroll
        for (int r = 0; r < 4; ++r) {
            const int row = mt * 16 + quad * 4 + r;
            const float s = ssqs[0][row] + ssqs[1][row] + ssqs[2][row] + ssqs[3][row];
            rn[mt][r] = 1.0f / fmaxf(sqrtf(s), 1e-12f);
        }

    if constexpr (!LAST) {
        #pragma unroll
        for (int j = 0; j < JMAX; ++j) {
            const int nt = wv + 4 * j;
            if (nt < NT) {
                const int col = nt * 16 + n16;
                if (col < F_OUT) {
                    #pragma unroll
                    for (int mt = 0; mt < 3; ++mt)
                        #pragma unroll
                        for (int r = 0; r < 4; ++r) {
                            const int row = mt * 16 + quad * 4 + r;
                            if (row < 40) {
                                const float v = fmaxf(acc[j][mt][r] * rn[mt][r], 0.f);
                                xout[(size_t)(R0 + row) * XS + col] = f2bf(v);
                            }
                        }
                }
            }
        }
    } else {
        // fused molecule segment-sum: rows 0..19 -> mol 2*bid, 20..39 -> 2*bid+1
        #pragma unroll
        for (int j = 0; j < JMAX; ++j) {
            float m0 = 0.f, m1 = 0.f;
            #pragma unroll
            for (int mt = 0; mt < 3; ++mt)
                #pragma unroll
                for (int r = 0; r < 4; ++r) {
                    const int row = mt * 16 + quad * 4 + r;
                    if (row < 40) {
                        const float v = fmaxf(acc[j][mt][r] * rn[mt][r], 0.f);
                        if (row < 20) m0 += v; else m1 += v;
                    }
                }
            m0 += __shfl_xor(m0, 16); m0 += __shfl_xor(m0, 32);
            m1 += __shfl_xor(m1, 16); m1 += __shfl_xor(m1, 32);
            if (quad == 0) {
                const int col = (wv + 4 * j) * 16 + n16;
                molout[(size_t)(2 * blockIdx.x)     * 512 + col] = m0;
                molout[(size_t)(2 * blockIdx.x + 1) * 512 + col] = m1;
            }
        }
    }
}

extern "C" void kernel_launch(void* const* d_in, const int* in_sizes, int n_in,
                              void* d_out, int out_size, void* d_ws, size_t ws_size,
                              hipStream_t stream) {
    const bool sig_order = (in_sizes[3] != 100000);

    const float* atomf = (const float*)d_in[0];   // [500000,62]
    const float* bondf = (const float*)d_in[1];   // [600000,6]
    const int *an1, *bn1, *an2, *bn2, *an3, *bn3, *an4, *bn4;
    const float *Ws0, *bs0, *Wd0, *bd0;
    const float *Ws1, *bs1, *Wd1, *bd1;
    const float *Ws2, *bs2, *Wd2, *bd2;

    if (!sig_order) {
        an1 = (const int*)d_in[2];  bn1 = (const int*)d_in[3];
        an2 = (const int*)d_in[4];  bn2 = (const int*)d_in[5];
        an3 = (const int*)d_in[6];  bn3 = (const int*)d_in[7];
        an4 = (const int*)d_in[8];  bn4 = (const int*)d_in[9];
        Ws0 = (const float*)d_in[11]; bs0 = (const float*)d_in[12];
        Wd0 = (const float*)d_in[13]; bd0 = (const float*)d_in[14];
        Ws1 = (const float*)d_in[15]; bs1 = (const float*)d_in[16];
        Wd1 = (const float*)d_in[17]; bd1 = (const float*)d_in[18];
        Ws2 = (const float*)d_in[19]; bs2 = (const float*)d_in[20];
        Wd2 = (const float*)d_in[21]; bd2 = (const float*)d_in[22];
    } else {
        an1 = (const int*)d_in[2];  an2 = (const int*)d_in[3];
        an3 = (const int*)d_in[4];  an4 = (const int*)d_in[5];
        bn1 = (const int*)d_in[6];  bn2 = (const int*)d_in[7];
        bn3 = (const int*)d_in[8];  bn4 = (const int*)d_in[9];
        Ws0 = (const float*)d_in[11]; bs0 = (const float*)d_in[12];
        Ws1 = (const float*)d_in[13]; bs1 = (const float*)d_in[14];
        Ws2 = (const float*)d_in[15]; bs2 = (const float*)d_in[16];
        Wd0 = (const float*)d_in[17]; bd0 = (const float*)d_in[18];
        Wd1 = (const float*)d_in[19]; bd1 = (const float*)d_in[20];
        Wd2 = (const float*)d_in[21]; bd2 = (const float*)d_in[22];
    }

    // workspace layout (<= ~201.3 MB; R3 used 208 MB successfully)
    char* w = (char*)d_ws;
    unsigned short* x1  = (unsigned short*)w;                        // 100,000,000 B
    unsigned short* x2  = (unsigned short*)(w + 100000000);          // 100,000,000 B
    unsigned short* Wt0 = (unsigned short*)(w + 200000000);          // 4*112*160*2 = 143360
    float*          bc0 = (float*)(w + 200143360);                   // 1792
    unsigned short* Wt1 = (unsigned short*)(w + 200145152);          // 4*112*224*2 = 200704
    float*          bc1 = (float*)(w + 200345856);                   // 1792
    unsigned short* Wt2 = (unsigned short*)(w + 200347648);          // 4*512*224*2 = 917504
    float*          bc2 = (float*)(w + 201265152);                   // 8192

    prep_weights<<<(4 * 112 * 160 + 255) / 256, 256, 0, stream>>>(
        Ws0, bs0, Wd0, bd0, 62, 100, 112, 160, Wt0, bc0);
    prep_weights<<<(4 * 112 * 224 + 255) / 256, 256, 0, stream>>>(
        Ws1, bs1, Wd1, bd1, 100, 100, 112, 224, Wt1, bc1);
    prep_weights<<<(4 * 512 * 224 + 255) / 256, 256, 0, stream>>>(
        Ws2, bs2, Wd2, bd2, 100, 512, 512, 224, Wt2, bc2);

    dim3 grid(12500), block(256);
    layer_mfma<62, 100, 112, false, false><<<grid, block, 0, stream>>>(
        atomf, bondf, an1, bn1, an2, bn2, an3, bn3, an4, bn4,
        Wt0, bc0, x1, nullptr);
    layer_mfma<100, 100, 112, false, true><<<grid, block, 0, stream>>>(
        x1, bondf, an1, bn1, an2, bn2, an3, bn3, an4, bn4,
        Wt1, bc1, x2, nullptr);
    layer_mfma<100, 512, 512, true, true><<<grid, block, 0, stream>>>(
        x2, bondf, an1, bn1, an2, bn2, an3, bn3, an4, bn4,
        Wt2, bc2, nullptr, (float*)d_out);
}

// Round 5
// 899.481 us; speedup vs baseline: 3.7820x; 1.6741x over previous
//
#include <hip/hip_runtime.h>

// NeuralConvNetwork (Duvenaud fingerprint GNN), MI355X.
// Round 5: attack the latency-bound gather (R4: layer2 760us with MfmaUtil 7.5%,
// VALUBusy 21%, HBM 6% -> ~1 outstanding load/wave in the runtime-deg neighbor
// loop). Changes:
//   - gather templated on DEG (block-uniform): indices loaded first, then ALL
//     5x(1+DEG) row-chunk loads issued into register arrays before any use ->
//     ~25 outstanding loads/wave.
//   - bond gather: one thread per row, all DEG x 3 float2 loads batched.
//   - H layout: self@0 (100), nbr@104 (100), bond@208 (6), KP=224; x stride 100.
//   - GEMM: b-fragments hoisted per k-step; epilogue unchanged (fused norm+relu,
//     layer 3 fuses per-molecule segment sum in-register).

#define XS 100   // bf16 elems per intermediate activation row (exact)

typedef __attribute__((ext_vector_type(8))) short short8;
typedef __attribute__((ext_vector_type(4))) float float4v;

__device__ __forceinline__ float bf2f(unsigned u) { return __uint_as_float(u << 16); }
__device__ __forceinline__ unsigned short f2bf(float f) {
    unsigned b = __float_as_uint(f);
    return (unsigned short)((b + 0x7FFFu + ((b >> 16) & 1u)) >> 16);  // RNE
}
__device__ __forceinline__ unsigned pack2(float a, float b) {
    return (unsigned)f2bf(a) | ((unsigned)f2bf(b) << 16);
}

// ---- weight prep: Wt[dg][n][k]; k<F_IN -> Ws[k][n], SELF_PAD<=k<SELF_PAD+F_IN
//      -> Wd[dg][k-SELF_PAD][n], 2*SELF_PAD<=k<2*SELF_PAD+6 -> Wd bond rows.
__global__ void prep_weights(const float* __restrict__ Ws, const float* __restrict__ bs,
                             const float* __restrict__ Wd, const float* __restrict__ bd,
                             int F_IN, int F_OUT, int F_OUT_PAD, int KP, int SELF_PAD,
                             unsigned short* __restrict__ Wt, float* __restrict__ bc)
{
    int id = blockIdx.x * 256 + threadIdx.x;
    int total = 4 * F_OUT_PAD * KP;
    if (id >= total) return;
    int k  = id % KP;
    int nq = (id / KP) % F_OUT_PAD;
    int dg = id / (KP * F_OUT_PAD);
    float v = 0.f;
    if (nq < F_OUT) {
        if (k < F_IN)                                   v = Ws[(size_t)k * F_OUT + nq];
        else if (k >= SELF_PAD && k < SELF_PAD + F_IN)  v = Wd[((size_t)dg * (F_IN + 6) + (k - SELF_PAD)) * F_OUT + nq];
        else if (k >= 2 * SELF_PAD && k < 2 * SELF_PAD + 6)
            v = Wd[((size_t)dg * (F_IN + 6) + F_IN + (k - 2 * SELF_PAD)) * F_OUT + nq];
    }
    Wt[id] = f2bf(v);
    if (k == 0)
        bc[dg * F_OUT_PAD + nq] = (nq < F_OUT) ? (bs[nq] + bd[(size_t)dg * F_OUT + nq]) : 0.f;
}

// ---- gather, bf16 input rows of XS=100. H: self@[0,100), nbr@[104,204),
//      bond@[208,214), zeros elsewhere up to KP=224.
template<int DEG, int SP>
__device__ __forceinline__ void gather_bf16(
    unsigned short* Hs, const unsigned short* __restrict__ x,
    const float* __restrict__ bondf,
    const int* __restrict__ an, const int* __restrict__ bn,
    int seg, int B40)
{
    const int tid = threadIdx.x;
    const int ch  = tid & 31;
    const int rr  = tid >> 5;                       // 0..7

    if (ch < 25) {                                  // 25 x uint2 = 100 elems/row
        int ai[5][DEG];
        #pragma unroll
        for (int p = 0; p < 5; ++p) {
            const int ri = B40 + rr + 8 * p;
            #pragma unroll
            for (int d = 0; d < DEG; ++d) ai[p][d] = an[(size_t)ri * DEG + d];
        }
        uint2 sv[5], nv[5][DEG];
        #pragma unroll
        for (int p = 0; p < 5; ++p) {
            const int atom = seg + B40 + rr + 8 * p;
            sv[p] = *(const uint2*)(x + (size_t)atom * XS + ch * 4);
            #pragma unroll
            for (int d = 0; d < DEG; ++d)
                nv[p][d] = *(const uint2*)(x + (size_t)ai[p][d] * XS + ch * 4);
        }
        #pragma unroll
        for (int p = 0; p < 5; ++p) {
            unsigned short* hrow = Hs + (rr + 8 * p) * SP;
            *(uint2*)(hrow + ch * 4) = sv[p];       // self: bit copy
            float s0 = 0.f, s1 = 0.f, s2 = 0.f, s3 = 0.f;
            #pragma unroll
            for (int d = 0; d < DEG; ++d) {
                s0 += bf2f(nv[p][d].x & 0xFFFFu); s1 += bf2f(nv[p][d].x >> 16);
                s2 += bf2f(nv[p][d].y & 0xFFFFu); s3 += bf2f(nv[p][d].y >> 16);
            }
            uint2 o; o.x = pack2(s0, s1); o.y = pack2(s2, s3);
            *(uint2*)(hrow + 104 + ch * 4) = o;
        }
    }
    if (tid < 40) {                                 // bond: one row per thread
        const int ri = B40 + tid;
        int bi[DEG];
        #pragma unroll
        for (int d = 0; d < DEG; ++d) bi[d] = bn[(size_t)ri * DEG + d];
        float2 v0[DEG], v1[DEG], v2[DEG];
        #pragma unroll
        for (int d = 0; d < DEG; ++d) {
            const float* bp = bondf + (size_t)bi[d] * 6;
            v0[d] = *(const float2*)bp;
            v1[d] = *(const float2*)(bp + 2);
            v2[d] = *(const float2*)(bp + 4);
        }
        float s0 = 0.f, s1 = 0.f, s2 = 0.f, s3 = 0.f, s4 = 0.f, s5 = 0.f;
        #pragma unroll
        for (int d = 0; d < DEG; ++d) {
            s0 += v0[d].x; s1 += v0[d].y; s2 += v1[d].x;
            s3 += v1[d].y; s4 += v2[d].x; s5 += v2[d].y;
        }
        unsigned short* hrow = Hs + tid * SP;
        uint4 w; w.x = pack2(s0, s1); w.y = pack2(s2, s3); w.z = pack2(s4, s5); w.w = 0;
        *(uint4*)(hrow + 208) = w;                  // cols 208-215
        *(uint4*)(hrow + 216) = make_uint4(0, 0, 0, 0);  // cols 216-223
    }
    // zero pads: self [100,104) + nbr [204,208) rows 0..39; pad rows 40..47 full
    for (int i = tid; i < 80; i += 256) {
        unsigned short* p = Hs + (i >> 1) * SP + ((i & 1) ? 204 : 100);
        *(uint2*)p = make_uint2(0, 0);
    }
    for (int i = tid; i < 8 * 28; i += 256) {       // 8 rows x 28 x 16B = 224 cols
        *(uint4*)(Hs + (40 + i / 28) * SP + (i % 28) * 8) = make_uint4(0, 0, 0, 0);
    }
}

// ---- gather, fp32 input rows of 62. H: self@[0,62), nbr@[64,126),
//      bond@[128,134), zeros elsewhere up to KP=160.
template<int DEG, int SP>
__device__ __forceinline__ void gather_f32(
    unsigned short* Hs, const float* __restrict__ x,
    const float* __restrict__ bondf,
    const int* __restrict__ an, const int* __restrict__ bn,
    int seg, int B40)
{
    const int tid = threadIdx.x;
    const int ch  = tid & 31;
    const int rr  = tid >> 5;

    if (ch < 31) {                                  // 31 x float2 = 62 elems/row
        int ai[5][DEG];
        #pragma unroll
        for (int p = 0; p < 5; ++p) {
            const int ri = B40 + rr + 8 * p;
            #pragma unroll
            for (int d = 0; d < DEG; ++d) ai[p][d] = an[(size_t)ri * DEG + d];
        }
        float2 sv[5], nv[5][DEG];
        #pragma unroll
        for (int p = 0; p < 5; ++p) {
            const int atom = seg + B40 + rr + 8 * p;
            sv[p] = *(const float2*)(x + (size_t)atom * 62 + ch * 2);
            #pragma unroll
            for (int d = 0; d < DEG; ++d)
                nv[p][d] = *(const float2*)(x + (size_t)ai[p][d] * 62 + ch * 2);
        }
        #pragma unroll
        for (int p = 0; p < 5; ++p) {
            unsigned short* hrow = Hs + (rr + 8 * p) * SP;
            *(unsigned*)(hrow + ch * 2) = pack2(sv[p].x, sv[p].y);
            float s0 = 0.f, s1 = 0.f;
            #pragma unroll
            for (int d = 0; d < DEG; ++d) { s0 += nv[p][d].x; s1 += nv[p][d].y; }
            *(unsigned*)(hrow + 64 + ch * 2) = pack2(s0, s1);
        }
    }
    if (tid < 40) {                                 // bond
        const int ri = B40 + tid;
        int bi[DEG];
        #pragma unroll
        for (int d = 0; d < DEG; ++d) bi[d] = bn[(size_t)ri * DEG + d];
        float2 v0[DEG], v1[DEG], v2[DEG];
        #pragma unroll
        for (int d = 0; d < DEG; ++d) {
            const float* bp = bondf + (size_t)bi[d] * 6;
            v0[d] = *(const float2*)bp;
            v1[d] = *(const float2*)(bp + 2);
            v2[d] = *(const float2*)(bp + 4);
        }
        float s0 = 0.f, s1 = 0.f, s2 = 0.f, s3 = 0.f, s4 = 0.f, s5 = 0.f;
        #pragma unroll
        for (int d = 0; d < DEG; ++d) {
            s0 += v0[d].x; s1 += v0[d].y; s2 += v1[d].x;
            s3 += v1[d].y; s4 += v2[d].x; s5 += v2[d].y;
        }
        unsigned short* hrow = Hs + tid * SP;
        uint4 w; w.x = pack2(s0, s1); w.y = pack2(s2, s3); w.z = pack2(s4, s5); w.w = 0;
        *(uint4*)(hrow + 128) = w;                  // cols 128-135
        *(uint4*)(hrow + 136) = make_uint4(0, 0, 0, 0);
        *(uint4*)(hrow + 144) = make_uint4(0, 0, 0, 0);
        *(uint4*)(hrow + 152) = make_uint4(0, 0, 0, 0);
    }
    for (int i = tid; i < 80; i += 256) {           // self pad [62,64), nbr pad [126,128)
        *(unsigned*)(Hs + (i >> 1) * SP + ((i & 1) ? 126 : 62)) = 0;
    }
    for (int i = tid; i < 8 * 20; i += 256) {       // pad rows 40..47, 160 cols
        *(uint4*)(Hs + (40 + i / 20) * SP + (i % 20) * 8) = make_uint4(0, 0, 0, 0);
    }
}

template<int F_IN, int F_OUT, int F_OUT_PAD, int SELF_PAD, bool LAST, bool BF16IN>
__global__ __launch_bounds__(256) void layer_mfma(
    const void* __restrict__ xin,
    const float* __restrict__ bondf,
    const int* __restrict__ an1, const int* __restrict__ bn1,
    const int* __restrict__ an2, const int* __restrict__ bn2,
    const int* __restrict__ an3, const int* __restrict__ bn3,
    const int* __restrict__ an4, const int* __restrict__ bn4,
    const unsigned short* __restrict__ Wt,  // [4][F_OUT_PAD][KP] bf16
    const float* __restrict__ bcomb,        // [4][F_OUT_PAD] fp32
    unsigned short* __restrict__ xout,      // layers 0/1: [500000, XS] bf16
    float* __restrict__ molout)             // layer 2:    [25000, 512] fp32
{
    constexpr int KP   = (2 * SELF_PAD + 6 + 31) & ~31;   // 160 / 224
    constexpr int SP   = KP + 8;
    constexpr int NT   = F_OUT_PAD / 16;
    constexpr int JMAX = (NT + 3) / 4;

    __shared__ __align__(16) unsigned short Hs[48 * SP];
    __shared__ float ssqs[4][48];

    const int R0 = blockIdx.x * 40;
    int deg, seg;
    if (R0 < 100000)      { deg = 1; seg = 0;      }
    else if (R0 < 275000) { deg = 2; seg = 100000; }
    else if (R0 < 425000) { deg = 3; seg = 275000; }
    else                  { deg = 4; seg = 425000; }
    const int B40 = R0 - seg;

    if constexpr (BF16IN) {
        const unsigned short* x = (const unsigned short*)xin;
        switch (deg) {
            case 1: gather_bf16<1, SP>(Hs, x, bondf, an1, bn1, seg, B40); break;
            case 2: gather_bf16<2, SP>(Hs, x, bondf, an2, bn2, seg, B40); break;
            case 3: gather_bf16<3, SP>(Hs, x, bondf, an3, bn3, seg, B40); break;
            default: gather_bf16<4, SP>(Hs, x, bondf, an4, bn4, seg, B40); break;
        }
    } else {
        const float* x = (const float*)xin;
        switch (deg) {
            case 1: gather_f32<1, SP>(Hs, x, bondf, an1, bn1, seg, B40); break;
            case 2: gather_f32<2, SP>(Hs, x, bondf, an2, bn2, seg, B40); break;
            case 3: gather_f32<3, SP>(Hs, x, bondf, an3, bn3, seg, B40); break;
            default: gather_f32<4, SP>(Hs, x, bondf, an4, bn4, seg, B40); break;
        }
    }
    __syncthreads();

    // ---- MFMA GEMM: 3 M-tiles (48 rows) x NT N-tiles, K = KP
    const int lane = threadIdx.x & 63;
    const int wv   = threadIdx.x >> 6;
    const int n16  = lane & 15;
    const int quad = lane >> 4;

    float4v acc[JMAX][3];
    #pragma unroll
    for (int j = 0; j < JMAX; ++j)
        #pragma unroll
        for (int mt = 0; mt < 3; ++mt)
            acc[j][mt] = (float4v){0.f, 0.f, 0.f, 0.f};

    const unsigned short* Wb = Wt + (size_t)(deg - 1) * F_OUT_PAD * KP;

    for (int kk = 0; kk < KP; kk += 32) {
        short8 a[3];
        #pragma unroll
        for (int mt = 0; mt < 3; ++mt)
            a[mt] = *(const short8*)&Hs[(mt * 16 + n16) * SP + kk + quad * 8];
        short8 b[JMAX];
        #pragma unroll
        for (int j = 0; j < JMAX; ++j) {
            const int nt = wv + 4 * j;
            if (nt < NT)
                b[j] = *(const short8*)(Wb + (size_t)(nt * 16 + n16) * KP + kk + quad * 8);
        }
        #pragma unroll
        for (int j = 0; j < JMAX; ++j) {
            const int nt = wv + 4 * j;
            if (nt < NT)
                #pragma unroll
                for (int mt = 0; mt < 3; ++mt)
                    acc[j][mt] = __builtin_amdgcn_mfma_f32_16x16x32_bf16(
                        a[mt], b[j], acc[j][mt], 0, 0, 0);
        }
    }

    // ---- epilogue: bias, row ssq (quad shfl + cross-wave LDS), normalize
    // C/D layout: col = nt*16 + n16, row = mt*16 + quad*4 + r
    float ssq[3][4];
    #pragma unroll
    for (int mt = 0; mt < 3; ++mt)
        #pragma unroll
        for (int r = 0; r < 4; ++r) ssq[mt][r] = 0.f;

    #pragma unroll
    for (int j = 0; j < JMAX; ++j) {
        const int nt = wv + 4 * j;
        if (nt < NT) {
            const float bj = bcomb[(deg - 1) * F_OUT_PAD + nt * 16 + n16];
            #pragma unroll
            for (int mt = 0; mt < 3; ++mt)
                #pragma unroll
                for (int r = 0; r < 4; ++r) {
                    float t = acc[j][mt][r] + bj;
                    acc[j][mt][r] = t;
                    ssq[mt][r] += t * t;
                }
        }
    }
    #pragma unroll
    for (int off = 1; off <= 8; off <<= 1)
        #pragma unroll
        for (int mt = 0; mt < 3; ++mt)
            #pragma unroll
            for (int r = 0; r < 4; ++r)
                ssq[mt][r] += __shfl_xor(ssq[mt][r], off);
    if (n16 == 0)
        #pragma unroll
        for (int mt = 0; mt < 3; ++mt)
            #pragma unroll
            for (int r = 0; r < 4; ++r)
                ssqs[wv][mt * 16 + quad * 4 + r] = ssq[mt][r];
    __syncthreads();

    float rn[3][4];
    #pragma unroll
    for (int mt = 0; mt < 3; ++mt)
        #pragma unroll
        for (int r = 0; r < 4; ++r) {
            const int row = mt * 16 + quad * 4 + r;
            const float s = ssqs[0][row] + ssqs[1][row] + ssqs[2][row] + ssqs[3][row];
            rn[mt][r] = 1.0f / fmaxf(sqrtf(s), 1e-12f);
        }

    if constexpr (!LAST) {
        #pragma unroll
        for (int j = 0; j < JMAX; ++j) {
            const int nt = wv + 4 * j;
            if (nt < NT) {
                const int col = nt * 16 + n16;
                if (col < F_OUT) {
                    #pragma unroll
                    for (int mt = 0; mt < 3; ++mt)
                        #pragma unroll
                        for (int r = 0; r < 4; ++r) {
                            const int row = mt * 16 + quad * 4 + r;
                            if (row < 40) {
                                const float v = fmaxf(acc[j][mt][r] * rn[mt][r], 0.f);
                                xout[(size_t)(R0 + row) * XS + col] = f2bf(v);
                            }
                        }
                }
            }
        }
    } else {
        // fused molecule segment-sum: rows 0..19 -> mol 2*bid, 20..39 -> 2*bid+1
        #pragma unroll
        for (int j = 0; j < JMAX; ++j) {
            float m0 = 0.f, m1 = 0.f;
            #pragma unroll
            for (int mt = 0; mt < 3; ++mt)
                #pragma unroll
                for (int r = 0; r < 4; ++r) {
                    const int row = mt * 16 + quad * 4 + r;
                    if (row < 40) {
                        const float v = fmaxf(acc[j][mt][r] * rn[mt][r], 0.f);
                        if (row < 20) m0 += v; else m1 += v;
                    }
                }
            m0 += __shfl_xor(m0, 16); m0 += __shfl_xor(m0, 32);
            m1 += __shfl_xor(m1, 16); m1 += __shfl_xor(m1, 32);
            if (quad == 0) {
                const int col = (wv + 4 * j) * 16 + n16;
                molout[(size_t)(2 * blockIdx.x)     * 512 + col] = m0;
                molout[(size_t)(2 * blockIdx.x + 1) * 512 + col] = m1;
            }
        }
    }
}

extern "C" void kernel_launch(void* const* d_in, const int* in_sizes, int n_in,
                              void* d_out, int out_size, void* d_ws, size_t ws_size,
                              hipStream_t stream) {
    const bool sig_order = (in_sizes[3] != 100000);

    const float* atomf = (const float*)d_in[0];   // [500000,62]
    const float* bondf = (const float*)d_in[1];   // [600000,6]
    const int *an1, *bn1, *an2, *bn2, *an3, *bn3, *an4, *bn4;
    const float *Ws0, *bs0, *Wd0, *bd0;
    const float *Ws1, *bs1, *Wd1, *bd1;
    const float *Ws2, *bs2, *Wd2, *bd2;

    if (!sig_order) {
        an1 = (const int*)d_in[2];  bn1 = (const int*)d_in[3];
        an2 = (const int*)d_in[4];  bn2 = (const int*)d_in[5];
        an3 = (const int*)d_in[6];  bn3 = (const int*)d_in[7];
        an4 = (const int*)d_in[8];  bn4 = (const int*)d_in[9];
        Ws0 = (const float*)d_in[11]; bs0 = (const float*)d_in[12];
        Wd0 = (const float*)d_in[13]; bd0 = (const float*)d_in[14];
        Ws1 = (const float*)d_in[15]; bs1 = (const float*)d_in[16];
        Wd1 = (const float*)d_in[17]; bd1 = (const float*)d_in[18];
        Ws2 = (const float*)d_in[19]; bs2 = (const float*)d_in[20];
        Wd2 = (const float*)d_in[21]; bd2 = (const float*)d_in[22];
    } else {
        an1 = (const int*)d_in[2];  an2 = (const int*)d_in[3];
        an3 = (const int*)d_in[4];  an4 = (const int*)d_in[5];
        bn1 = (const int*)d_in[6];  bn2 = (const int*)d_in[7];
        bn3 = (const int*)d_in[8];  bn4 = (const int*)d_in[9];
        Ws0 = (const float*)d_in[11]; bs0 = (const float*)d_in[12];
        Ws1 = (const float*)d_in[13]; bs1 = (const float*)d_in[14];
        Ws2 = (const float*)d_in[15]; bs2 = (const float*)d_in[16];
        Wd0 = (const float*)d_in[17]; bd0 = (const float*)d_in[18];
        Wd1 = (const float*)d_in[19]; bd1 = (const float*)d_in[20];
        Wd2 = (const float*)d_in[21]; bd2 = (const float*)d_in[22];
    }

    // workspace layout (201,273,344 B total — same as proven R4 footprint)
    char* w = (char*)d_ws;
    unsigned short* x1  = (unsigned short*)w;                        // 100,000,000 B
    unsigned short* x2  = (unsigned short*)(w + 100000000);          // 100,000,000 B
    unsigned short* Wt0 = (unsigned short*)(w + 200000000);          // 4*112*160*2 = 143360
    float*          bc0 = (float*)(w + 200143360);                   // 1792
    unsigned short* Wt1 = (unsigned short*)(w + 200145152);          // 4*112*224*2 = 200704
    float*          bc1 = (float*)(w + 200345856);                   // 1792
    unsigned short* Wt2 = (unsigned short*)(w + 200347648);          // 4*512*224*2 = 917504
    float*          bc2 = (float*)(w + 201265152);                   // 8192

    prep_weights<<<(4 * 112 * 160 + 255) / 256, 256, 0, stream>>>(
        Ws0, bs0, Wd0, bd0, 62, 100, 112, 160, 64, Wt0, bc0);
    prep_weights<<<(4 * 112 * 224 + 255) / 256, 256, 0, stream>>>(
        Ws1, bs1, Wd1, bd1, 100, 100, 112, 224, 104, Wt1, bc1);
    prep_weights<<<(4 * 512 * 224 + 255) / 256, 256, 0, stream>>>(
        Ws2, bs2, Wd2, bd2, 100, 512, 512, 224, 104, Wt2, bc2);

    dim3 grid(12500), block(256);
    layer_mfma<62, 100, 112, 64, false, false><<<grid, block, 0, stream>>>(
        atomf, bondf, an1, bn1, an2, bn2, an3, bn3, an4, bn4,
        Wt0, bc0, x1, nullptr);
    layer_mfma<100, 100, 112, 104, false, true><<<grid, block, 0, stream>>>(
        x1, bondf, an1, bn1, an2, bn2, an3, bn3, an4, bn4,
        Wt1, bc1, x2, nullptr);
    layer_mfma<100, 512, 512, 104, true, true><<<grid, block, 0, stream>>>(
        x2, bondf, an1, bn1, an2, bn2, an3, bn3, an4, bn4,
        Wt2, bc2, nullptr, (float*)d_out);
}